// Round 2
// baseline (226.682 us; speedup 1.0000x reference)
//
#include <hip/hip_runtime.h>
#include <hip/hip_bf16.h>
#include <stdint.h>

#define S_LEN 4096
#define D_DIM 256
#define NBATCH 4
#define NKT 64   // 4096 / 64 keys per tile

typedef unsigned short u16;
typedef float  f32x4  __attribute__((ext_vector_type(4)));
typedef __bf16 bf16x8 __attribute__((ext_vector_type(8)));
typedef __bf16 bf16x4 __attribute__((ext_vector_type(4)));
typedef short  s16x8  __attribute__((ext_vector_type(8)));
typedef short  s16x4  __attribute__((ext_vector_type(4)));

__device__ __forceinline__ f32x4 mfma16(bf16x8 a, bf16x8 b, f32x4 c) {
  return __builtin_amdgcn_mfma_f32_16x16x32_bf16(a, b, c, 0, 0, 0);
}

__device__ __forceinline__ s16x4 cvt4(float x, float y, float z, float w) {
  bf16x4 b;
  b[0] = (__bf16)x; b[1] = (__bf16)y; b[2] = (__bf16)z; b[3] = (__bf16)w;
  return __builtin_bit_cast(s16x4, b);
}

__global__ void convert_bf16_kernel(const float* __restrict__ in,
                                    u16* __restrict__ out, int n4) {
  int i = blockIdx.x * blockDim.x + threadIdx.x;
  if (i >= n4) return;
  float4 f = reinterpret_cast<const float4*>(in)[i];
  reinterpret_cast<s16x4*>(out)[i] = cvt4(f.x, f.y, f.z, f.w);
}

// ---------------------------------------------------------------------------
// LDS layouts (all plain ds_read/ds_write; no transpose-read instructions):
//
// K tile:  Ks[64 k][256 d] bf16 row-major (512 B/row), byte ^= ((k&7)<<4).
//   QK^T A-fragment = 16B read per lane -> 8-way aliasing = b128 floor.
//
// V tile:  Vt[256 d][64 k] bf16 (V TRANSPOSED, 128 B/row), with PERMUTED
//   column order  col(k) = 16*((k>>2)&3) + 4*(k>>4) + (k&3)  and 16B-chunk
//   swizzle  byte ^= ((d&7)<<4).
//   Why: swapped QK^T leaves lane (g,h) holding P for keys
//   {16c + 4g + j : c=0..3, j=0..3} (slot (g, 4c'+j) of the PV A-operand
//   must be key (c')*16 + 4g + j, c'=c mod 2, per the m89 D-layout).  With
//   the column permutation those 16 keys sit at cols [16g, 16g+16) = two
//   contiguous 16B chunks per d-row -> PV B-fragments are 2 plain
//   ds_read_b128 per (lane, d-chunk), slot order matching P exactly.
//   The transpose is done at staging time in registers (static indices).
// ---------------------------------------------------------------------------

template<bool USE_WS>
__global__ __launch_bounds__(256, 1)
void attn_fwd_kernel(const float* __restrict__ Qg, const void* __restrict__ Kp,
                     const void* __restrict__ Vp, float* __restrict__ Og)
{
  __shared__ __align__(16) u16 Ks[64 * 256];   // 32 KiB
  __shared__ __align__(16) u16 Vt[256 * 64];   // 32 KiB

  const int wg   = blockIdx.x;                 // 256 WGs (1 per CU)
  const int swz  = (wg & 7) * 32 + (wg >> 3);  // bijective XCD swizzle
  const int b    = swz >> 6;
  const int qt   = swz & 63;
  const int tid  = threadIdx.x;
  const int wave = tid >> 6;
  const int lane = tid & 63;
  const int g    = lane >> 4;
  const int h    = lane & 15;

  // staging roles for V^T: thread = (k-block, d-chunk)
  const int kb  = tid & 15;    // keys 4*kb .. 4*kb+3
  const int dcq = tid >> 4;    // d in [16*dcq, 16*dcq+16)

  const int qbase = qt * 64 + wave * 16;

  // Q fragments (B-operand of swapped QK^T), pre-scaled by 1/sqrt(256)
  bf16x8 qf[8];
  {
    const float* qrow = Qg + ((size_t)b * S_LEN + qbase + h) * D_DIM;
    #pragma unroll
    for (int dc = 0; dc < 8; ++dc) {
      float4 f0 = *reinterpret_cast<const float4*>(qrow + dc * 32 + g * 8);
      float4 f1 = *reinterpret_cast<const float4*>(qrow + dc * 32 + g * 8 + 4);
      bf16x8 q;
      q[0] = (__bf16)(f0.x * 0.0625f); q[1] = (__bf16)(f0.y * 0.0625f);
      q[2] = (__bf16)(f0.z * 0.0625f); q[3] = (__bf16)(f0.w * 0.0625f);
      q[4] = (__bf16)(f1.x * 0.0625f); q[5] = (__bf16)(f1.y * 0.0625f);
      q[6] = (__bf16)(f1.z * 0.0625f); q[7] = (__bf16)(f1.w * 0.0625f);
      qf[dc] = q;
    }
  }

  f32x4 acc[16];
  const f32x4 fz = {0.f, 0.f, 0.f, 0.f};
  #pragma unroll
  for (int i = 0; i < 16; ++i) acc[i] = fz;
  float m_run = -1e30f;
  float l_run = 0.f;

  const u16*   Kb = USE_WS ? ((const u16*)Kp + (size_t)b * S_LEN * D_DIM) : (const u16*)nullptr;
  const u16*   Vb = USE_WS ? ((const u16*)Vp + (size_t)b * S_LEN * D_DIM) : (const u16*)nullptr;
  const float* Kf = USE_WS ? (const float*)nullptr : ((const float*)Kp + (size_t)b * S_LEN * D_DIM);
  const float* Vf = USE_WS ? (const float*)nullptr : ((const float*)Vp + (size_t)b * S_LEN * D_DIM);

  char* KsB = (char*)&Ks[0];
  char* VtB = (char*)&Vt[0];

  // PV read pointers (loop-invariant): lane (g,h), d-row d = dt*16 + h,
  // chunk position (32g + 16*half) ^ ((h&7)<<4); dt walks via offset dt*2048.
  const char* vpA = VtB + h * 128 + ((32 * g)      ^ ((h & 7) << 4));
  const char* vpB = VtB + h * 128 + ((32 * g + 16) ^ ((h & 7) << 4));

  for (int kt = 0; kt < NKT; ++kt) {
    __syncthreads();
    // ---- stage K tile (row-major, swizzled) ----
    if constexpr (USE_WS) {
      #pragma unroll
      for (int i = 0; i < 8; ++i) {
        int flat = i * 256 + tid;          // 2048 chunks of 8 bf16
        int kk = flat >> 5;
        int d  = (flat & 31) * 8;
        s16x8 kv = *reinterpret_cast<const s16x8*>(Kb + (size_t)(kt * 64 + kk) * D_DIM + d);
        *reinterpret_cast<s16x8*>(KsB + kk * 512 + ((d * 2) ^ ((kk & 7) << 4))) = kv;
      }
    } else {
      #pragma unroll
      for (int i = 0; i < 16; ++i) {
        int flat = i * 256 + tid;          // 4096 chunks of 4 f32
        int kk = flat >> 6;
        int d  = (flat & 63) * 4;
        float4 fk = *reinterpret_cast<const float4*>(Kf + (size_t)(kt * 64 + kk) * D_DIM + d);
        *reinterpret_cast<s16x4*>(KsB + kk * 512 + ((d * 2) ^ ((kk & 7) << 4))) = cvt4(fk.x, fk.y, fk.z, fk.w);
      }
    }
    // ---- stage V tile TRANSPOSED: thread owns 4(k) x 16(d) block ----
    {
      s16x8 lo[4], hi[4];
      if constexpr (USE_WS) {
        #pragma unroll
        for (int r = 0; r < 4; ++r) {
          const u16* src = Vb + (size_t)(kt * 64 + kb * 4 + r) * D_DIM + dcq * 16;
          lo[r] = *reinterpret_cast<const s16x8*>(src);
          hi[r] = *reinterpret_cast<const s16x8*>(src + 8);
        }
      } else {
        #pragma unroll
        for (int r = 0; r < 4; ++r) {
          const float* src = Vf + (size_t)(kt * 64 + kb * 4 + r) * D_DIM + dcq * 16;
          float4 f0 = *reinterpret_cast<const float4*>(src);
          float4 f1 = *reinterpret_cast<const float4*>(src + 4);
          float4 f2 = *reinterpret_cast<const float4*>(src + 8);
          float4 f3 = *reinterpret_cast<const float4*>(src + 12);
          lo[r] = __builtin_shufflevector(cvt4(f0.x, f0.y, f0.z, f0.w),
                                          cvt4(f1.x, f1.y, f1.z, f1.w), 0, 1, 2, 3, 4, 5, 6, 7);
          hi[r] = __builtin_shufflevector(cvt4(f2.x, f2.y, f2.z, f2.w),
                                          cvt4(f3.x, f3.y, f3.z, f3.w), 0, 1, 2, 3, 4, 5, 6, 7);
        }
      }
      // permuted column chunk base for keys 4*kb..4*kb+3:
      // Xw = 32*(kb&3) + 8*(kb>>2)
      const int Xw = 32 * (kb & 3) + 8 * (kb >> 2);
      #pragma unroll
      for (int j = 0; j < 8; ++j) {
        s16x4 c0, c1;
        c0[0] = lo[0][j]; c0[1] = lo[1][j]; c0[2] = lo[2][j]; c0[3] = lo[3][j];
        c1[0] = hi[0][j]; c1[1] = hi[1][j]; c1[2] = hi[2][j]; c1[3] = hi[3][j];
        const int d0 = dcq * 16 + j;        // d&7 = j&7 = j (j<8)
        const int d1 = d0 + 8;              // d&7 = j
        *reinterpret_cast<s16x4*>(VtB + d0 * 128 + (Xw ^ ((d0 & 7) << 4))) = c0;
        *reinterpret_cast<s16x4*>(VtB + d1 * 128 + (Xw ^ ((d1 & 7) << 4))) = c1;
      }
    }
    __syncthreads();

    // ---- QK^T swapped (A=K, B=Q): lane (g,h) reg r of tile t holds
    //      S[key = t*16 + 4g + r][q = h] ----
    f32x4 st[4];
    #pragma unroll
    for (int t = 0; t < 4; ++t) {
      f32x4 a = fz;
      const int row = t * 16 + h;
      const int sw  = (row & 7) << 4;
      #pragma unroll
      for (int dc = 0; dc < 8; ++dc) {
        s16x8 kfrag = *reinterpret_cast<const s16x8*>(KsB + row * 512 + ((dc * 64 + g * 16) ^ sw));
        a = mfma16(__builtin_bit_cast(bf16x8, kfrag), qf[dc], a);
      }
      st[t] = a;
    }

    // ---- online softmax (q = h; lane holds keys {t*16+4g+r}) ----
    float sv[16];
    #pragma unroll
    for (int t = 0; t < 4; ++t) {
      sv[t * 4 + 0] = st[t][0]; sv[t * 4 + 1] = st[t][1];
      sv[t * 4 + 2] = st[t][2]; sv[t * 4 + 3] = st[t][3];
    }
    float tmax = sv[0];
    #pragma unroll
    for (int i = 1; i < 16; ++i) tmax = fmaxf(tmax, sv[i]);
    tmax = fmaxf(tmax, __shfl_xor(tmax, 16));
    tmax = fmaxf(tmax, __shfl_xor(tmax, 32));
    const float mnew  = fmaxf(m_run, tmax);
    const float alpha = __expf(m_run - mnew);
    float psum = 0.f;
    #pragma unroll
    for (int i = 0; i < 16; ++i) { sv[i] = __expf(sv[i] - mnew); psum += sv[i]; }
    psum += __shfl_xor(psum, 16);
    psum += __shfl_xor(psum, 32);
    l_run = l_run * alpha + psum;
    m_run = mnew;

    // rescale O accumulators (O rows are q' = 4g+r; alpha lives at lane q)
    const float af0 = __shfl(alpha, g * 4 + 0);
    const float af1 = __shfl(alpha, g * 4 + 1);
    const float af2 = __shfl(alpha, g * 4 + 2);
    const float af3 = __shfl(alpha, g * 4 + 3);
    #pragma unroll
    for (int dt = 0; dt < 16; ++dt) {
      acc[dt][0] *= af0; acc[dt][1] *= af1; acc[dt][2] *= af2; acc[dt][3] *= af3;
    }

    // P -> bf16 A-fragments: pa0 slot 4c+j = key 16c+4g+j; pa1 = +32.
    bf16x8 pa0, pa1;
    #pragma unroll
    for (int j = 0; j < 8; ++j) { pa0[j] = (__bf16)sv[j]; pa1[j] = (__bf16)sv[8 + j]; }

    // ---- PV: B-fragments are contiguous b128 reads of permuted V^T ----
    #pragma unroll
    for (int dt = 0; dt < 16; ++dt) {
      s16x8 v0 = *reinterpret_cast<const s16x8*>(vpA + dt * 2048);
      s16x8 v1 = *reinterpret_cast<const s16x8*>(vpB + dt * 2048);
      acc[dt] = mfma16(pa0, __builtin_bit_cast(bf16x8, v0), acc[dt]);
      acc[dt] = mfma16(pa1, __builtin_bit_cast(bf16x8, v1), acc[dt]);
    }
  }

  // ---- epilogue: divide by row-sum, store fp32 ----
  float* orow0 = Og + ((size_t)b * S_LEN + qbase) * D_DIM;
  #pragma unroll
  for (int r = 0; r < 4; ++r) {
    const float inv = 1.f / __shfl(l_run, g * 4 + r);
    float* orow = orow0 + (size_t)(g * 4 + r) * D_DIM + h;
    #pragma unroll
    for (int dt = 0; dt < 16; ++dt) orow[dt * 16] = acc[dt][r] * inv;
  }
}

extern "C" void kernel_launch(void* const* d_in, const int* in_sizes, int n_in,
                              void* d_out, int out_size, void* d_ws, size_t ws_size,
                              hipStream_t stream)
{
  const float* Q = (const float*)d_in[0];
  const float* K = (const float*)d_in[1];
  const float* V = (const float*)d_in[2];
  float* O = (float*)d_out;

  const size_t nelem = (size_t)NBATCH * S_LEN * D_DIM;   // 4,194,304
  const size_t need  = 2 * nelem * sizeof(u16);          // 16 MiB

  if (ws_size >= need) {
    u16* Kb = (u16*)d_ws;
    u16* Vb = Kb + nelem;
    int n4 = (int)(nelem / 4);
    convert_bf16_kernel<<<n4 / 256, 256, 0, stream>>>(K, Kb, n4);
    convert_bf16_kernel<<<n4 / 256, 256, 0, stream>>>(V, Vb, n4);
    attn_fwd_kernel<true><<<256, 256, 0, stream>>>(Q, (const void*)Kb, (const void*)Vb, O);
  } else {
    attn_fwd_kernel<false><<<256, 256, 0, stream>>>(Q, (const void*)K, (const void*)V, O);
  }
}

// Round 4
// 177.906 us; speedup vs baseline: 1.2742x; 1.2742x over previous
//
#include <hip/hip_runtime.h>
#include <hip/hip_bf16.h>
#include <stdint.h>

#define S_LEN 4096
#define D_DIM 256
#define NBATCH 4
#define NKT 64   // 4096 / 64 keys per tile

typedef unsigned short u16;
typedef float  f32x4  __attribute__((ext_vector_type(4)));
typedef __bf16 bf16x8 __attribute__((ext_vector_type(8)));
typedef __bf16 bf16x4 __attribute__((ext_vector_type(4)));
typedef short  s16x8  __attribute__((ext_vector_type(8)));
typedef short  s16x4  __attribute__((ext_vector_type(4)));

__device__ __forceinline__ f32x4 mfma16(bf16x8 a, bf16x8 b, f32x4 c) {
  return __builtin_amdgcn_mfma_f32_16x16x32_bf16(a, b, c, 0, 0, 0);
}

__device__ __forceinline__ s16x4 cvt4(float x, float y, float z, float w) {
  bf16x4 b;
  b[0] = (__bf16)x; b[1] = (__bf16)y; b[2] = (__bf16)z; b[3] = (__bf16)w;
  return __builtin_bit_cast(s16x4, b);
}

__global__ void convert_bf16_kernel(const float* __restrict__ in,
                                    u16* __restrict__ out, int n4) {
  int i = blockIdx.x * blockDim.x + threadIdx.x;
  if (i >= n4) return;
  float4 f = reinterpret_cast<const float4*>(in)[i];
  reinterpret_cast<s16x4*>(out)[i] = cvt4(f.x, f.y, f.z, f.w);
}

// ---------------------------------------------------------------------------
// LDS layouts (identical to the verified R2 kernel):
//  K tile:  Ks[64 k][256 d] bf16 row-major (512 B/row), byte ^= ((k&7)<<4).
//  V tile:  Vt[256 d][64 k] bf16 transposed, permuted cols
//           col(k) = 16*((k>>2)&3) + 4*(k>>4) + (k&3), byte ^= ((d&7)<<4).
// R4 = R3 with the compile fix (helper inlined): T14 async prefetch
// (tile kt+1 -> regs during compute of kt, regs -> LDS between barriers),
// T5 setprio around MFMA clusters, T13 defer-max.
// ---------------------------------------------------------------------------

// compute one staged tile from LDS into the online-softmax state
__device__ __forceinline__
void compute_tile(const char* KsB, const char* vpA, const char* vpB,
                  const bf16x8 (&qf)[8], f32x4 (&acc)[16],
                  float& m_run, float& l_run, int g, int h)
{
  const f32x4 fz = {0.f, 0.f, 0.f, 0.f};

  // ---- QK^T swapped (A=K, B=Q): lane (g,h) reg r of tile t holds
  //      S[key = t*16 + 4g + r][q = h] ----
  f32x4 st[4];
  __builtin_amdgcn_s_setprio(1);
  #pragma unroll
  for (int t = 0; t < 4; ++t) {
    f32x4 a = fz;
    const int row = t * 16 + h;
    const int sw  = (row & 7) << 4;
    #pragma unroll
    for (int dc = 0; dc < 8; ++dc) {
      s16x8 kfrag = *reinterpret_cast<const s16x8*>(KsB + row * 512 + ((dc * 64 + g * 16) ^ sw));
      a = mfma16(__builtin_bit_cast(bf16x8, kfrag), qf[dc], a);
    }
    st[t] = a;
  }
  __builtin_amdgcn_s_setprio(0);

  // ---- online softmax (q = h; lane holds keys {t*16+4g+r}) ----
  float sv[16];
  #pragma unroll
  for (int t = 0; t < 4; ++t) {
    sv[t * 4 + 0] = st[t][0]; sv[t * 4 + 1] = st[t][1];
    sv[t * 4 + 2] = st[t][2]; sv[t * 4 + 3] = st[t][3];
  }
  float tmax = sv[0];
  #pragma unroll
  for (int i = 1; i < 16; ++i) tmax = fmaxf(tmax, sv[i]);
  tmax = fmaxf(tmax, __shfl_xor(tmax, 16));
  tmax = fmaxf(tmax, __shfl_xor(tmax, 32));

  // T13 defer-max: only rescale when the tile max grew past m_run + 8
  if (!__all(tmax <= m_run + 8.0f)) {
    const float mnew  = fmaxf(m_run, tmax);
    const float alpha = __expf(m_run - mnew);
    l_run *= alpha;
    const float af0 = __shfl(alpha, g * 4 + 0);
    const float af1 = __shfl(alpha, g * 4 + 1);
    const float af2 = __shfl(alpha, g * 4 + 2);
    const float af3 = __shfl(alpha, g * 4 + 3);
    #pragma unroll
    for (int dt = 0; dt < 16; ++dt) {
      acc[dt][0] *= af0; acc[dt][1] *= af1; acc[dt][2] *= af2; acc[dt][3] *= af3;
    }
    m_run = mnew;
  }

  float psum = 0.f;
  #pragma unroll
  for (int i = 0; i < 16; ++i) { sv[i] = __expf(sv[i] - m_run); psum += sv[i]; }
  psum += __shfl_xor(psum, 16);
  psum += __shfl_xor(psum, 32);
  l_run += psum;

  // P -> bf16 A-fragments: pa0 slot 4c+j = key 16c+4g+j; pa1 = +32.
  bf16x8 pa0, pa1;
  #pragma unroll
  for (int j = 0; j < 8; ++j) { pa0[j] = (__bf16)sv[j]; pa1[j] = (__bf16)sv[8 + j]; }

  // ---- PV: B-fragments are contiguous b128 reads of permuted V^T ----
  __builtin_amdgcn_s_setprio(1);
  #pragma unroll
  for (int dt = 0; dt < 16; ++dt) {
    s16x8 v0 = *reinterpret_cast<const s16x8*>(vpA + dt * 2048);
    s16x8 v1 = *reinterpret_cast<const s16x8*>(vpB + dt * 2048);
    acc[dt] = mfma16(pa0, __builtin_bit_cast(bf16x8, v0), acc[dt]);
    acc[dt] = mfma16(pa1, __builtin_bit_cast(bf16x8, v1), acc[dt]);
  }
  __builtin_amdgcn_s_setprio(0);
}

template<bool USE_WS>
__global__ __launch_bounds__(256, 1)
void attn_fwd_kernel(const float* __restrict__ Qg, const void* __restrict__ Kp,
                     const void* __restrict__ Vp, float* __restrict__ Og)
{
  __shared__ __align__(16) u16 Ks[64 * 256];   // 32 KiB
  __shared__ __align__(16) u16 Vt[256 * 64];   // 32 KiB

  const int wg   = blockIdx.x;                 // 256 WGs (1 per CU)
  const int swz  = (wg & 7) * 32 + (wg >> 3);  // bijective XCD swizzle
  const int b    = swz >> 6;
  const int qt   = swz & 63;
  const int tid  = threadIdx.x;
  const int wave = tid >> 6;
  const int lane = tid & 63;
  const int g    = lane >> 4;
  const int h    = lane & 15;

  // staging roles: K thread = (row-block tid>>5, 16B-chunk tid&31);
  //                V thread = (k-block kb, d-chunk dcq)
  const int kb  = tid & 15;    // keys 4*kb .. 4*kb+3
  const int dcq = tid >> 4;    // d in [16*dcq, 16*dcq+16)

  const int qbase = qt * 64 + wave * 16;

  // Q fragments (B-operand of swapped QK^T), pre-scaled by 1/sqrt(256)
  bf16x8 qf[8];
  {
    const float* qrow = Qg + ((size_t)b * S_LEN + qbase + h) * D_DIM;
    #pragma unroll
    for (int dc = 0; dc < 8; ++dc) {
      float4 f0 = *reinterpret_cast<const float4*>(qrow + dc * 32 + g * 8);
      float4 f1 = *reinterpret_cast<const float4*>(qrow + dc * 32 + g * 8 + 4);
      bf16x8 q;
      q[0] = (__bf16)(f0.x * 0.0625f); q[1] = (__bf16)(f0.y * 0.0625f);
      q[2] = (__bf16)(f0.z * 0.0625f); q[3] = (__bf16)(f0.w * 0.0625f);
      q[4] = (__bf16)(f1.x * 0.0625f); q[5] = (__bf16)(f1.y * 0.0625f);
      q[6] = (__bf16)(f1.z * 0.0625f); q[7] = (__bf16)(f1.w * 0.0625f);
      qf[dc] = q;
    }
  }

  f32x4 acc[16];
  const f32x4 fz = {0.f, 0.f, 0.f, 0.f};
  #pragma unroll
  for (int i = 0; i < 16; ++i) acc[i] = fz;
  float m_run = -1e30f;
  float l_run = 0.f;

  char* KsB = (char*)&Ks[0];
  char* VtB = (char*)&Vt[0];

  // PV read pointers (loop-invariant)
  const char* vpA = VtB + h * 128 + ((32 * g)      ^ ((h & 7) << 4));
  const char* vpB = VtB + h * 128 + ((32 * g + 16) ^ ((h & 7) << 4));

  if constexpr (USE_WS) {
    const u16* Kb = (const u16*)Kp + (size_t)b * S_LEN * D_DIM;
    const u16* Vb = (const u16*)Vp + (size_t)b * S_LEN * D_DIM;

    // per-thread invariant staging addresses
    const u16* ksrc = Kb + (size_t)(tid >> 5) * D_DIM + (tid & 31) * 8;
    char*      kdst = KsB + (tid >> 5) * 512 + (((tid & 31) * 16) ^ ((tid >> 5) << 4));
    const u16* vsrc = Vb + (size_t)(kb * 4) * D_DIM + dcq * 16;
    const int  Xw   = 32 * (kb & 3) + 8 * (kb >> 2);   // permuted col chunk base

    s16x8 kreg[8], vlo[4], vhi[4];

    // ---- prologue: load + store tile 0 ----
    #pragma unroll
    for (int i = 0; i < 8; ++i)
      kreg[i] = *reinterpret_cast<const s16x8*>(ksrc + (size_t)i * 8 * D_DIM);
    #pragma unroll
    for (int r = 0; r < 4; ++r) {
      const u16* s = vsrc + (size_t)r * D_DIM;
      vlo[r] = *reinterpret_cast<const s16x8*>(s);
      vhi[r] = *reinterpret_cast<const s16x8*>(s + 8);
    }
    #pragma unroll
    for (int i = 0; i < 8; ++i)
      *reinterpret_cast<s16x8*>(kdst + i * 4096) = kreg[i];
    #pragma unroll
    for (int j = 0; j < 8; ++j) {
      s16x4 c0, c1;
      c0[0] = vlo[0][j]; c0[1] = vlo[1][j]; c0[2] = vlo[2][j]; c0[3] = vlo[3][j];
      c1[0] = vhi[0][j]; c1[1] = vhi[1][j]; c1[2] = vhi[2][j]; c1[3] = vhi[3][j];
      const int d0 = dcq * 16 + j;
      const int d1 = d0 + 8;
      *reinterpret_cast<s16x4*>(VtB + d0 * 128 + (Xw ^ ((d0 & 7) << 4))) = c0;
      *reinterpret_cast<s16x4*>(VtB + d1 * 128 + (Xw ^ ((d1 & 7) << 4))) = c1;
    }
    __syncthreads();

    // ---- main loop: prefetch kt+1 in regs, compute kt, swap via barriers ----
    for (int kt = 0; kt < NKT - 1; ++kt) {
      const size_t nb = (size_t)(kt + 1) * 64 * D_DIM;
      #pragma unroll
      for (int i = 0; i < 8; ++i)
        kreg[i] = *reinterpret_cast<const s16x8*>(ksrc + nb + (size_t)i * 8 * D_DIM);
      #pragma unroll
      for (int r = 0; r < 4; ++r) {
        const u16* s = vsrc + nb + (size_t)r * D_DIM;
        vlo[r] = *reinterpret_cast<const s16x8*>(s);
        vhi[r] = *reinterpret_cast<const s16x8*>(s + 8);
      }

      compute_tile(KsB, vpA, vpB, qf, acc, m_run, l_run, g, h);

      __syncthreads();   // all waves done reading current LDS tile
      #pragma unroll
      for (int i = 0; i < 8; ++i)
        *reinterpret_cast<s16x8*>(kdst + i * 4096) = kreg[i];
      #pragma unroll
      for (int j = 0; j < 8; ++j) {
        s16x4 c0, c1;
        c0[0] = vlo[0][j]; c0[1] = vlo[1][j]; c0[2] = vlo[2][j]; c0[3] = vlo[3][j];
        c1[0] = vhi[0][j]; c1[1] = vhi[1][j]; c1[2] = vhi[2][j]; c1[3] = vhi[3][j];
        const int d0 = dcq * 16 + j;
        const int d1 = d0 + 8;
        *reinterpret_cast<s16x4*>(VtB + d0 * 128 + (Xw ^ ((d0 & 7) << 4))) = c0;
        *reinterpret_cast<s16x4*>(VtB + d1 * 128 + (Xw ^ ((d1 & 7) << 4))) = c1;
      }
      __syncthreads();   // new tile visible
    }
    compute_tile(KsB, vpA, vpB, qf, acc, m_run, l_run, g, h);

  } else {
    // fallback (fp32 inputs, serial staging) — used only if d_ws is too small
    const float* Kf = (const float*)Kp + (size_t)b * S_LEN * D_DIM;
    const float* Vf = (const float*)Vp + (size_t)b * S_LEN * D_DIM;
    for (int kt = 0; kt < NKT; ++kt) {
      __syncthreads();
      #pragma unroll
      for (int i = 0; i < 16; ++i) {
        int flat = i * 256 + tid;
        int kk = flat >> 6;
        int d  = (flat & 63) * 4;
        float4 fk = *reinterpret_cast<const float4*>(Kf + (size_t)(kt * 64 + kk) * D_DIM + d);
        *reinterpret_cast<s16x4*>(KsB + kk * 512 + ((d * 2) ^ ((kk & 7) << 4))) = cvt4(fk.x, fk.y, fk.z, fk.w);
      }
      {
        s16x8 lo[4], hi[4];
        #pragma unroll
        for (int r = 0; r < 4; ++r) {
          const float* src = Vf + (size_t)(kt * 64 + kb * 4 + r) * D_DIM + dcq * 16;
          float4 f0 = *reinterpret_cast<const float4*>(src);
          float4 f1 = *reinterpret_cast<const float4*>(src + 4);
          float4 f2 = *reinterpret_cast<const float4*>(src + 8);
          float4 f3 = *reinterpret_cast<const float4*>(src + 12);
          lo[r] = __builtin_shufflevector(cvt4(f0.x, f0.y, f0.z, f0.w),
                                          cvt4(f1.x, f1.y, f1.z, f1.w), 0, 1, 2, 3, 4, 5, 6, 7);
          hi[r] = __builtin_shufflevector(cvt4(f2.x, f2.y, f2.z, f2.w),
                                          cvt4(f3.x, f3.y, f3.z, f3.w), 0, 1, 2, 3, 4, 5, 6, 7);
        }
        const int Xw = 32 * (kb & 3) + 8 * (kb >> 2);
        #pragma unroll
        for (int j = 0; j < 8; ++j) {
          s16x4 c0, c1;
          c0[0] = lo[0][j]; c0[1] = lo[1][j]; c0[2] = lo[2][j]; c0[3] = lo[3][j];
          c1[0] = hi[0][j]; c1[1] = hi[1][j]; c1[2] = hi[2][j]; c1[3] = hi[3][j];
          const int d0 = dcq * 16 + j;
          const int d1 = d0 + 8;
          *reinterpret_cast<s16x4*>(VtB + d0 * 128 + (Xw ^ ((d0 & 7) << 4))) = c0;
          *reinterpret_cast<s16x4*>(VtB + d1 * 128 + (Xw ^ ((d1 & 7) << 4))) = c1;
        }
      }
      __syncthreads();
      compute_tile(KsB, vpA, vpB, qf, acc, m_run, l_run, g, h);
    }
  }

  // ---- epilogue: divide by row-sum, store fp32 ----
  float* orow0 = Og + ((size_t)b * S_LEN + qbase) * D_DIM;
  #pragma unroll
  for (int r = 0; r < 4; ++r) {
    const float inv = 1.f / __shfl(l_run, g * 4 + r);
    float* orow = orow0 + (size_t)(g * 4 + r) * D_DIM + h;
    #pragma unroll
    for (int dt = 0; dt < 16; ++dt) orow[dt * 16] = acc[dt][r] * inv;
  }
}

extern "C" void kernel_launch(void* const* d_in, const int* in_sizes, int n_in,
                              void* d_out, int out_size, void* d_ws, size_t ws_size,
                              hipStream_t stream)
{
  const float* Q = (const float*)d_in[0];
  const float* K = (const float*)d_in[1];
  const float* V = (const float*)d_in[2];
  float* O = (float*)d_out;

  const size_t nelem = (size_t)NBATCH * S_LEN * D_DIM;   // 4,194,304
  const size_t need  = 2 * nelem * sizeof(u16);          // 16 MiB

  if (ws_size >= need) {
    u16* Kb = (u16*)d_ws;
    u16* Vb = Kb + nelem;
    int n4 = (int)(nelem / 4);
    convert_bf16_kernel<<<n4 / 256, 256, 0, stream>>>(K, Kb, n4);
    convert_bf16_kernel<<<n4 / 256, 256, 0, stream>>>(V, Vb, n4);
    attn_fwd_kernel<true><<<256, 256, 0, stream>>>(Q, (const void*)Kb, (const void*)Vb, O);
  } else {
    attn_fwd_kernel<false><<<256, 256, 0, stream>>>(Q, (const void*)K, (const void*)V, O);
  }
}

// Round 5
// 152.768 us; speedup vs baseline: 1.4838x; 1.1645x over previous
//
#include <hip/hip_runtime.h>
#include <hip/hip_bf16.h>
#include <stdint.h>

#define S_LEN 4096
#define D_DIM 256
#define NBATCH 4
#define NKT 64    // 4096 / 64 keys per tile
#define NSUP 32   // super-steps: each processes tiles {2s, 2s+1}

typedef unsigned short u16;
typedef float  f32x4  __attribute__((ext_vector_type(4)));
typedef __bf16 bf16x8 __attribute__((ext_vector_type(8)));
typedef __bf16 bf16x4 __attribute__((ext_vector_type(4)));
typedef short  s16x8  __attribute__((ext_vector_type(8)));
typedef short  s16x4  __attribute__((ext_vector_type(4)));

__device__ __forceinline__ f32x4 mfma16(bf16x8 a, bf16x8 b, f32x4 c) {
  return __builtin_amdgcn_mfma_f32_16x16x32_bf16(a, b, c, 0, 0, 0);
}

__device__ __forceinline__ s16x4 cvt4(float x, float y, float z, float w) {
  bf16x4 b;
  b[0] = (__bf16)x; b[1] = (__bf16)y; b[2] = (__bf16)z; b[3] = (__bf16)w;
  return __builtin_bit_cast(s16x4, b);
}

__global__ void convert_bf16_kernel(const float* __restrict__ in,
                                    u16* __restrict__ out, int n4) {
  int i = blockIdx.x * blockDim.x + threadIdx.x;
  if (i >= n4) return;
  float4 f = reinterpret_cast<const float4*>(in)[i];
  reinterpret_cast<s16x4*>(out)[i] = cvt4(f.x, f.y, f.z, f.w);
}

// ---------------------------------------------------------------------------
// R5: 8-wave split-K structure. Two 64KB tile buffers in 128KB LDS.
//   group A = waves 0-3 computes EVEN tiles from buf0,
//   group B = waves 4-7 computes ODD  tiles from buf1,
//   both run the byte-identical verified per-wave pipeline (R2/R4 layouts):
//     K tile:  [64 k][256 d] bf16, byte ^= ((k&7)<<4)
//     V tile:  [256 d][64 k] bf16 transposed, permuted cols
//              col(k)=16*((k>>2)&3)+4*(k>>4)+(k&3), byte ^= ((d&7)<<4)
//   plus T14 reg-prefetch, T5 setprio, T13 defer-max.
//   End: merge the two online-softmax states via LDS (A-waves store).
// ---------------------------------------------------------------------------

__device__ __forceinline__
void compute_tile(const char* KsB, const char* vpA, const char* vpB,
                  const bf16x8 (&qf)[8], f32x4 (&acc)[16],
                  float& m_run, float& l_run, int g, int h)
{
  const f32x4 fz = {0.f, 0.f, 0.f, 0.f};

  // ---- QK^T swapped (A=K, B=Q): lane (g,h) reg r of tile t holds
  //      S[key = t*16 + 4g + r][q = h] ----
  f32x4 st[4];
  __builtin_amdgcn_s_setprio(1);
  #pragma unroll
  for (int t = 0; t < 4; ++t) {
    f32x4 a = fz;
    const int row = t * 16 + h;
    const int sw  = (row & 7) << 4;
    #pragma unroll
    for (int dc = 0; dc < 8; ++dc) {
      s16x8 kfrag = *reinterpret_cast<const s16x8*>(KsB + row * 512 + ((dc * 64 + g * 16) ^ sw));
      a = mfma16(__builtin_bit_cast(bf16x8, kfrag), qf[dc], a);
    }
    st[t] = a;
  }
  __builtin_amdgcn_s_setprio(0);

  // ---- online softmax (q = h; lane holds keys {t*16+4g+r}) ----
  float sv[16];
  #pragma unroll
  for (int t = 0; t < 4; ++t) {
    sv[t * 4 + 0] = st[t][0]; sv[t * 4 + 1] = st[t][1];
    sv[t * 4 + 2] = st[t][2]; sv[t * 4 + 3] = st[t][3];
  }
  float tmax = sv[0];
  #pragma unroll
  for (int i = 1; i < 16; ++i) tmax = fmaxf(tmax, sv[i]);
  tmax = fmaxf(tmax, __shfl_xor(tmax, 16));
  tmax = fmaxf(tmax, __shfl_xor(tmax, 32));

  // T13 defer-max: only rescale when the tile max grew past m_run + 8
  if (!__all(tmax <= m_run + 8.0f)) {
    const float mnew  = fmaxf(m_run, tmax);
    const float alpha = __expf(m_run - mnew);
    l_run *= alpha;
    const float af0 = __shfl(alpha, g * 4 + 0);
    const float af1 = __shfl(alpha, g * 4 + 1);
    const float af2 = __shfl(alpha, g * 4 + 2);
    const float af3 = __shfl(alpha, g * 4 + 3);
    #pragma unroll
    for (int dt = 0; dt < 16; ++dt) {
      acc[dt][0] *= af0; acc[dt][1] *= af1; acc[dt][2] *= af2; acc[dt][3] *= af3;
    }
    m_run = mnew;
  }

  float psum = 0.f;
  #pragma unroll
  for (int i = 0; i < 16; ++i) { sv[i] = __expf(sv[i] - m_run); psum += sv[i]; }
  psum += __shfl_xor(psum, 16);
  psum += __shfl_xor(psum, 32);
  l_run += psum;

  // P -> bf16 A-fragments: pa0 slot 4c+j = key 16c+4g+j; pa1 = +32.
  bf16x8 pa0, pa1;
  #pragma unroll
  for (int j = 0; j < 8; ++j) { pa0[j] = (__bf16)sv[j]; pa1[j] = (__bf16)sv[8 + j]; }

  // ---- PV: B-fragments are contiguous b128 reads of permuted V^T ----
  __builtin_amdgcn_s_setprio(1);
  #pragma unroll
  for (int dt = 0; dt < 16; ++dt) {
    s16x8 v0 = *reinterpret_cast<const s16x8*>(vpA + dt * 2048);
    s16x8 v1 = *reinterpret_cast<const s16x8*>(vpB + dt * 2048);
    acc[dt] = mfma16(pa0, __builtin_bit_cast(bf16x8, v0), acc[dt]);
    acc[dt] = mfma16(pa1, __builtin_bit_cast(bf16x8, v1), acc[dt]);
  }
  __builtin_amdgcn_s_setprio(0);
}

template<bool USE_WS>
__global__ __launch_bounds__(512, 1)
void attn_fwd_kernel(const float* __restrict__ Qg, const void* __restrict__ Kp,
                     const void* __restrict__ Vp, float* __restrict__ Og)
{
  __shared__ __align__(16) char smem[131072];   // 2 x (32KB Ks + 32KB Vt)

  const int wg   = blockIdx.x;                  // 256 WGs (1 per CU)
  const int swz  = (wg & 7) * 32 + (wg >> 3);   // bijective XCD swizzle
  const int b    = swz >> 6;
  const int qt   = swz & 63;
  const int tid  = threadIdx.x;
  const int wave = tid >> 6;                    // 0..7
  const int lane = tid & 63;
  const int g    = lane >> 4;
  const int h    = lane & 15;
  const int gid  = tid >> 8;                    // 0 = group A, 1 = group B
  const int ltid = tid & 255;                   // intra-group thread id
  const int wq   = wave & 3;                    // q-slot within group

  // staging roles (intra-group): K thread = (row-block ltid>>5, chunk ltid&31)
  //                              V thread = (k-block kb, d-chunk dcq)
  const int kb  = ltid & 15;
  const int dcq = ltid >> 4;

  char* KsB = smem + gid * 65536;
  char* VtB = KsB + 32768;

  const int qbase = qt * 64 + wq * 16;

  // Q fragments (B-operand of swapped QK^T), pre-scaled by 1/sqrt(256)
  bf16x8 qf[8];
  {
    const float* qrow = Qg + ((size_t)b * S_LEN + qbase + h) * D_DIM;
    #pragma unroll
    for (int dc = 0; dc < 8; ++dc) {
      float4 f0 = *reinterpret_cast<const float4*>(qrow + dc * 32 + g * 8);
      float4 f1 = *reinterpret_cast<const float4*>(qrow + dc * 32 + g * 8 + 4);
      bf16x8 q;
      q[0] = (__bf16)(f0.x * 0.0625f); q[1] = (__bf16)(f0.y * 0.0625f);
      q[2] = (__bf16)(f0.z * 0.0625f); q[3] = (__bf16)(f0.w * 0.0625f);
      q[4] = (__bf16)(f1.x * 0.0625f); q[5] = (__bf16)(f1.y * 0.0625f);
      q[6] = (__bf16)(f1.z * 0.0625f); q[7] = (__bf16)(f1.w * 0.0625f);
      qf[dc] = q;
    }
  }

  f32x4 acc[16];
  const f32x4 fz = {0.f, 0.f, 0.f, 0.f};
  #pragma unroll
  for (int i = 0; i < 16; ++i) acc[i] = fz;
  float m_run = -1e30f;
  float l_run = 0.f;

  // PV read pointers (loop-invariant, buffer-local)
  const char* vpA = VtB + h * 128 + ((32 * g)      ^ ((h & 7) << 4));
  const char* vpB = VtB + h * 128 + ((32 * g + 16) ^ ((h & 7) << 4));

  if constexpr (USE_WS) {
    const u16* Kb = (const u16*)Kp + (size_t)b * S_LEN * D_DIM;
    const u16* Vb = (const u16*)Vp + (size_t)b * S_LEN * D_DIM;

    const u16* ksrc = Kb + (size_t)(ltid >> 5) * D_DIM + (ltid & 31) * 8;
    char*      kdst = KsB + (ltid >> 5) * 512 + (((ltid & 31) * 16) ^ ((ltid >> 5) << 4));
    const u16* vsrc = Vb + (size_t)(kb * 4) * D_DIM + dcq * 16;
    const int  Xw   = 32 * (kb & 3) + 8 * (kb >> 2);

    s16x8 kreg[8], vlo[4], vhi[4];

    // ---- prologue: group g loads + stores tile gid ----
    {
      const size_t nb = (size_t)gid * 64 * D_DIM;
      #pragma unroll
      for (int i = 0; i < 8; ++i)
        kreg[i] = *reinterpret_cast<const s16x8*>(ksrc + nb + (size_t)i * 8 * D_DIM);
      #pragma unroll
      for (int r = 0; r < 4; ++r) {
        const u16* s = vsrc + nb + (size_t)r * D_DIM;
        vlo[r] = *reinterpret_cast<const s16x8*>(s);
        vhi[r] = *reinterpret_cast<const s16x8*>(s + 8);
      }
      #pragma unroll
      for (int i = 0; i < 8; ++i)
        *reinterpret_cast<s16x8*>(kdst + i * 4096) = kreg[i];
      #pragma unroll
      for (int j = 0; j < 8; ++j) {
        s16x4 c0, c1;
        c0[0] = vlo[0][j]; c0[1] = vlo[1][j]; c0[2] = vlo[2][j]; c0[3] = vlo[3][j];
        c1[0] = vhi[0][j]; c1[1] = vhi[1][j]; c1[2] = vhi[2][j]; c1[3] = vhi[3][j];
        const int d0 = dcq * 16 + j;
        const int d1 = d0 + 8;
        *reinterpret_cast<s16x4*>(VtB + d0 * 128 + (Xw ^ ((d0 & 7) << 4))) = c0;
        *reinterpret_cast<s16x4*>(VtB + d1 * 128 + (Xw ^ ((d1 & 7) << 4))) = c1;
      }
    }
    __syncthreads();

    // ---- main loop: prefetch tile 2(s+1)+gid, compute tile 2s+gid ----
    for (int s = 0; s < NSUP - 1; ++s) {
      const size_t nb = (size_t)(2 * (s + 1) + gid) * 64 * D_DIM;
      #pragma unroll
      for (int i = 0; i < 8; ++i)
        kreg[i] = *reinterpret_cast<const s16x8*>(ksrc + nb + (size_t)i * 8 * D_DIM);
      #pragma unroll
      for (int r = 0; r < 4; ++r) {
        const u16* sp = vsrc + nb + (size_t)r * D_DIM;
        vlo[r] = *reinterpret_cast<const s16x8*>(sp);
        vhi[r] = *reinterpret_cast<const s16x8*>(sp + 8);
      }

      compute_tile(KsB, vpA, vpB, qf, acc, m_run, l_run, g, h);

      __syncthreads();   // everyone done reading current tiles
      #pragma unroll
      for (int i = 0; i < 8; ++i)
        *reinterpret_cast<s16x8*>(kdst + i * 4096) = kreg[i];
      #pragma unroll
      for (int j = 0; j < 8; ++j) {
        s16x4 c0, c1;
        c0[0] = vlo[0][j]; c0[1] = vlo[1][j]; c0[2] = vlo[2][j]; c0[3] = vlo[3][j];
        c1[0] = vhi[0][j]; c1[1] = vhi[1][j]; c1[2] = vhi[2][j]; c1[3] = vhi[3][j];
        const int d0 = dcq * 16 + j;
        const int d1 = d0 + 8;
        *reinterpret_cast<s16x4*>(VtB + d0 * 128 + (Xw ^ ((d0 & 7) << 4))) = c0;
        *reinterpret_cast<s16x4*>(VtB + d1 * 128 + (Xw ^ ((d1 & 7) << 4))) = c1;
      }
      __syncthreads();   // new tiles visible
    }
    compute_tile(KsB, vpA, vpB, qf, acc, m_run, l_run, g, h);

  } else {
    // fallback (fp32 inputs, serial staging) — used only if d_ws is too small
    const float* Kf = (const float*)Kp + (size_t)b * S_LEN * D_DIM;
    const float* Vf = (const float*)Vp + (size_t)b * S_LEN * D_DIM;
    for (int s = 0; s < NSUP; ++s) {
      const int kt = 2 * s + gid;
      __syncthreads();
      #pragma unroll
      for (int i = 0; i < 16; ++i) {
        int flat = i * 256 + ltid;
        int kk = flat >> 6;
        int d  = (flat & 63) * 4;
        float4 fk = *reinterpret_cast<const float4*>(Kf + (size_t)(kt * 64 + kk) * D_DIM + d);
        *reinterpret_cast<s16x4*>(KsB + kk * 512 + ((d * 2) ^ ((kk & 7) << 4))) = cvt4(fk.x, fk.y, fk.z, fk.w);
      }
      {
        s16x8 lo[4], hi[4];
        #pragma unroll
        for (int r = 0; r < 4; ++r) {
          const float* src = Vf + (size_t)(kt * 64 + kb * 4 + r) * D_DIM + dcq * 16;
          float4 f0 = *reinterpret_cast<const float4*>(src);
          float4 f1 = *reinterpret_cast<const float4*>(src + 4);
          float4 f2 = *reinterpret_cast<const float4*>(src + 8);
          float4 f3 = *reinterpret_cast<const float4*>(src + 12);
          lo[r] = __builtin_shufflevector(cvt4(f0.x, f0.y, f0.z, f0.w),
                                          cvt4(f1.x, f1.y, f1.z, f1.w), 0, 1, 2, 3, 4, 5, 6, 7);
          hi[r] = __builtin_shufflevector(cvt4(f2.x, f2.y, f2.z, f2.w),
                                          cvt4(f3.x, f3.y, f3.z, f3.w), 0, 1, 2, 3, 4, 5, 6, 7);
        }
        const int Xw = 32 * (kb & 3) + 8 * (kb >> 2);
        #pragma unroll
        for (int j = 0; j < 8; ++j) {
          s16x4 c0, c1;
          c0[0] = lo[0][j]; c0[1] = lo[1][j]; c0[2] = lo[2][j]; c0[3] = lo[3][j];
          c1[0] = hi[0][j]; c1[1] = hi[1][j]; c1[2] = hi[2][j]; c1[3] = hi[3][j];
          const int d0 = dcq * 16 + j;
          const int d1 = d0 + 8;
          *reinterpret_cast<s16x4*>(VtB + d0 * 128 + (Xw ^ ((d0 & 7) << 4))) = c0;
          *reinterpret_cast<s16x4*>(VtB + d1 * 128 + (Xw ^ ((d1 & 7) << 4))) = c1;
        }
      }
      __syncthreads();
      compute_tile(KsB, vpA, vpB, qf, acc, m_run, l_run, g, h);
    }
  }

  // ---- merge group B's state into group A, then epilogue (A-waves) ----
  __syncthreads();   // all compute done; tile buffers are now dead
  // accM: [bw 0..3][lane 0..63][dt 0..15] float4, 16B-swizzled; 64KB at smem
  // mlM : [bw*16 + h] float2 (m, l); at smem + 65536
  float2* mlM = reinterpret_cast<float2*>(smem + 65536);
  if (gid == 1) {
    const int bw = wave - 4;
    char* base = smem + bw * 16384 + lane * 256;
    #pragma unroll
    for (int dt = 0; dt < 16; ++dt) {
      float4 v; v.x = acc[dt][0]; v.y = acc[dt][1]; v.z = acc[dt][2]; v.w = acc[dt][3];
      *reinterpret_cast<float4*>(base + (dt * 16 ^ ((lane & 7) << 4))) = v;
    }
    if (g == 0) { float2 ml; ml.x = m_run; ml.y = l_run; mlM[bw * 16 + h] = ml; }
  }
  __syncthreads();
  if (gid == 0) {
    const float2 ml = mlM[wave * 16 + h];
    const float mB = ml.x, lB = ml.y;
    const float m  = fmaxf(m_run, mB);
    const float sA = __expf(m_run - m);
    const float sB = __expf(mB - m);
    const float l  = l_run * sA + lB * sB;
    float aA[4], aB[4], inv[4];
    #pragma unroll
    for (int r = 0; r < 4; ++r) {
      aA[r]  = __shfl(sA, g * 4 + r);
      aB[r]  = __shfl(sB, g * 4 + r);
      inv[r] = 1.f / __shfl(l, g * 4 + r);
    }
    const char* base = smem + wave * 16384 + lane * 256;
    float* orow0 = Og + ((size_t)b * S_LEN + qbase) * D_DIM;
    #pragma unroll
    for (int dt = 0; dt < 16; ++dt) {
      float4 ab = *reinterpret_cast<const float4*>(base + (dt * 16 ^ ((lane & 7) << 4)));
      orow0[(size_t)(g * 4 + 0) * D_DIM + h + dt * 16] = (acc[dt][0] * aA[0] + ab.x * aB[0]) * inv[0];
      orow0[(size_t)(g * 4 + 1) * D_DIM + h + dt * 16] = (acc[dt][1] * aA[1] + ab.y * aB[1]) * inv[1];
      orow0[(size_t)(g * 4 + 2) * D_DIM + h + dt * 16] = (acc[dt][2] * aA[2] + ab.z * aB[2]) * inv[2];
      orow0[(size_t)(g * 4 + 3) * D_DIM + h + dt * 16] = (acc[dt][3] * aA[3] + ab.w * aB[3]) * inv[3];
    }
  }
}

extern "C" void kernel_launch(void* const* d_in, const int* in_sizes, int n_in,
                              void* d_out, int out_size, void* d_ws, size_t ws_size,
                              hipStream_t stream)
{
  const float* Q = (const float*)d_in[0];
  const float* K = (const float*)d_in[1];
  const float* V = (const float*)d_in[2];
  float* O = (float*)d_out;

  const size_t nelem = (size_t)NBATCH * S_LEN * D_DIM;   // 4,194,304
  const size_t need  = 2 * nelem * sizeof(u16);          // 16 MiB

  if (ws_size >= need) {
    u16* Kb = (u16*)d_ws;
    u16* Vb = Kb + nelem;
    int n4 = (int)(nelem / 4);
    convert_bf16_kernel<<<n4 / 256, 256, 0, stream>>>(K, Kb, n4);
    convert_bf16_kernel<<<n4 / 256, 256, 0, stream>>>(V, Vb, n4);
    attn_fwd_kernel<true><<<256, 512, 0, stream>>>(Q, (const void*)Kb, (const void*)Vb, O);
  } else {
    attn_fwd_kernel<false><<<256, 512, 0, stream>>>(Q, (const void*)K, (const void*)V, O);
  }
}